// Round 2
// baseline (1990.652 us; speedup 1.0000x reference)
//
#include <hip/hip_runtime.h>
#include <hip/hip_bf16.h>

#define BB 8
#define NN 9216       // 96*96
#define BN 73728      // BB*NN
#define CC 512
#define MM 128
#define DD 256
#define KK 300
#define DK 556        // DD+KK
#define PSTR 640      // 128 vote + 256 local + 256 query

// ---------------- pack [Wv | Wt | Wql] into Wcat[512][640] + bias[640] ----------------
__global__ __launch_bounds__(256) void pack_w(const float* __restrict__ Wv, const float* __restrict__ bv,
                                              const float* __restrict__ Wt, const float* __restrict__ bt,
                                              const float* __restrict__ Wql,
                                              float* __restrict__ Wcat, float* __restrict__ bias) {
    int gid = blockIdx.x * 256 + threadIdx.x;
    if (gid < 512 * PSTR) {
        int k = gid / PSTR, j = gid % PSTR;
        float v;
        if (j < 128)       v = Wv[k * 128 + j];
        else if (j < 384)  v = Wt[k * 256 + (j - 128)];
        else               v = Wql[k * 256 + (j - 384)];
        Wcat[gid] = v;
    }
    if (gid < PSTR) {
        bias[gid] = (gid < 128) ? bv[gid] : ((gid < 384) ? bt[gid - 128] : 0.0f);
    }
}

// ---------------- P[BN][640] = x[BN][512] @ Wcat[512][640] + bias ----------------
// 64x64 tile, 256 threads, 4x4 per thread, BK=32
__global__ __launch_bounds__(256) void proj_gemm(const float* __restrict__ A,
                                                 const float* __restrict__ Wcat,
                                                 const float* __restrict__ bias,
                                                 float* __restrict__ P) {
    __shared__ float AsT[32][68];   // transposed A tile, padded for alignment+banks
    __shared__ float Bs[32][64];
    int t = threadIdx.x;
    int tx = t & 15, ty = t >> 4;
    int n0 = blockIdx.x * 64;
    long row0 = (long)blockIdx.y * 64;
    float acc[4][4] = {};
    for (int k0 = 0; k0 < 512; k0 += 32) {
        __syncthreads();
        #pragma unroll
        for (int j = 0; j < 2; j++) {
            int idx = j * 256 + t;
            int r = idx >> 3, c4 = idx & 7;
            float4 v = *(const float4*)&A[(row0 + r) * CC + k0 + c4 * 4];
            AsT[c4 * 4 + 0][r] = v.x; AsT[c4 * 4 + 1][r] = v.y;
            AsT[c4 * 4 + 2][r] = v.z; AsT[c4 * 4 + 3][r] = v.w;
            int kk = idx >> 4, c4b = idx & 15;
            *(float4*)&Bs[kk][c4b * 4] = *(const float4*)&Wcat[(k0 + kk) * PSTR + n0 + c4b * 4];
        }
        __syncthreads();
        #pragma unroll
        for (int kk = 0; kk < 32; kk++) {
            float4 a4 = *(const float4*)&AsT[kk][ty * 4];
            float4 b4 = *(const float4*)&Bs[kk][tx * 4];
            float a[4] = {a4.x, a4.y, a4.z, a4.w};
            float b[4] = {b4.x, b4.y, b4.z, b4.w};
            #pragma unroll
            for (int i = 0; i < 4; i++)
                #pragma unroll
                for (int j = 0; j < 4; j++)
                    acc[i][j] += a[i] * b[j];
        }
    }
    float4 bb = *(const float4*)&bias[n0 + tx * 4];
    float bcol[4] = {bb.x, bb.y, bb.z, bb.w};
    #pragma unroll
    for (int i = 0; i < 4; i++) {
        float4 o;
        o.x = acc[i][0] + bcol[0]; o.y = acc[i][1] + bcol[1];
        o.z = acc[i][2] + bcol[2]; o.w = acc[i][3] + bcol[3];
        *(float4*)&P[(row0 + ty * 4 + i) * PSTR + n0 + tx * 4] = o;
    }
}

// ---------------- softmax over vote columns (P[:,0:128]), one wave per row ----------------
__global__ __launch_bounds__(256) void softmax_vote(float* __restrict__ P) {
    int wid = threadIdx.x >> 6, lane = threadIdx.x & 63;
    long row = (long)blockIdx.x * 4 + wid;
    float* p = &P[row * PSTR];
    float v0 = p[lane], v1 = p[lane + 64];
    float mx = fmaxf(v0, v1);
    #pragma unroll
    for (int off = 32; off; off >>= 1) mx = fmaxf(mx, __shfl_xor(mx, off));
    float e0 = __expf(v0 - mx), e1 = __expf(v1 - mx);
    float s = e0 + e1;
    #pragma unroll
    for (int off = 32; off; off >>= 1) s += __shfl_xor(s, off);
    float r = 1.0f / s;
    p[lane] = e0 * r;
    p[lane + 64] = e1 * r;
}

// ---------------- node[b][128][256] += vote^T @ local, split-K over n ----------------
__global__ __launch_bounds__(256) void node_gemm(const float* __restrict__ P, float* __restrict__ node) {
    __shared__ float Vs[32][33];
    __shared__ float Ls[32][64];
    int t = threadIdx.x;
    int blk = blockIdx.x;
    int nc = blk & 7, dt = (blk >> 3) & 3, mt = (blk >> 5) & 3, b = blk >> 7;
    int m0 = mt * 32, d0 = dt * 64, nbase = nc * 1152;
    long brow = (long)b * NN;
    int tx = t & 15, ty = t >> 4;
    float acc[2][4] = {};
    for (int nn = 0; nn < 1152; nn += 32) {
        __syncthreads();
        #pragma unroll
        for (int j = 0; j < 4; j++) {
            int idx = j * 256 + t;
            int r = idx >> 5, mm = idx & 31;
            Vs[r][mm] = P[(brow + nbase + nn + r) * PSTR + m0 + mm];
        }
        #pragma unroll
        for (int j = 0; j < 8; j++) {
            int idx = j * 256 + t;
            int r = idx >> 6, dd = idx & 63;
            Ls[r][dd] = P[(brow + nbase + nn + r) * PSTR + 128 + d0 + dd];
        }
        __syncthreads();
        #pragma unroll 8
        for (int n = 0; n < 32; n++) {
            float va[2] = {Vs[n][ty * 2], Vs[n][ty * 2 + 1]};
            float4 vb4 = *(const float4*)&Ls[n][tx * 4];
            float vb[4] = {vb4.x, vb4.y, vb4.z, vb4.w};
            #pragma unroll
            for (int i = 0; i < 2; i++)
                #pragma unroll
                for (int j = 0; j < 4; j++)
                    acc[i][j] += va[i] * vb[j];
        }
    }
    #pragma unroll
    for (int i = 0; i < 2; i++)
        #pragma unroll
        for (int j = 0; j < 4; j++)
            unsafeAtomicAdd(&node[(b * MM + m0 + ty * 2 + i) * DD + d0 + tx * 4 + j], acc[i][j]);
}

// ---------------- gcn[b][m][:] = [node_row | emb_row] @ Wg + bg ----------------
__global__ __launch_bounds__(256) void gcn_dense(const float* __restrict__ node, const float* __restrict__ emb,
                                                 const float* __restrict__ Wg, const float* __restrict__ bg,
                                                 float* __restrict__ gcn) {
    __shared__ float a[DK];
    int b = blockIdx.x >> 7, m = blockIdx.x & 127, t = threadIdx.x;
    for (int i = t; i < DK; i += 256)
        a[i] = (i < DD) ? node[(b * MM + m) * DD + i] : emb[m * KK + (i - DD)];
    __syncthreads();
    float acc = bg[t];
    for (int k = 0; k < DK; k++) acc += a[k] * Wg[k * DD + t];
    gcn[(b * MM + m) * DD + t] = acc;
}

// ---------------- evolved = relu(norm_adj @ gcn) ----------------
__global__ __launch_bounds__(256) void gcn_adj_relu(const float* __restrict__ adj, const float* __restrict__ gcn,
                                                    float* __restrict__ evo) {
    __shared__ float ar[128];
    int b = blockIdx.x >> 7, m = blockIdx.x & 127, t = threadIdx.x;
    if (t < 128) ar[t] = adj[m * MM + t];
    __syncthreads();
    float acc = 0.0f;
    for (int k = 0; k < MM; k++) acc += ar[k] * gcn[(b * MM + k) * DD + t];
    evo[(b * MM + m) * DD + t] = fmaxf(acc, 0.0f);
}

// ---------------- keyv = evolved @ Wkn ----------------
__global__ __launch_bounds__(256) void keyv_k(const float* __restrict__ evo, const float* __restrict__ Wkn,
                                              float* __restrict__ keyv) {
    __shared__ float e[DD];
    int b = blockIdx.x >> 7, m = blockIdx.x & 127, t = threadIdx.x;
    e[t] = evo[(b * MM + m) * DD + t];
    __syncthreads();
    float acc = 0.0f;
    for (int k = 0; k < DD; k++) acc += e[k] * Wkn[k * DD + t];
    keyv[(b * MM + m) * DD + t] = acc;
}

// ---------------- values = evolved @ Wm + bm ----------------
__global__ __launch_bounds__(512) void values_k(const float* __restrict__ evo, const float* __restrict__ Wm,
                                                const float* __restrict__ bm, float* __restrict__ vals) {
    __shared__ float e[DD];
    int b = blockIdx.x >> 7, m = blockIdx.x & 127, t = threadIdx.x;
    if (t < DD) e[t] = evo[(b * MM + m) * DD + t];
    __syncthreads();
    float acc = bm[t];
    for (int k = 0; k < DD; k++) acc += e[k] * Wm[k * CC + t];
    vals[(b * MM + m) * CC + t] = acc;
}

// ---------------- fused attention: logits -> softmax -> PV -> relu(x+out) ----------------
// one block per (b, 64-row tile)
__global__ __launch_bounds__(256) void attn_fused(const float* __restrict__ P, const float* __restrict__ keyv,
                                                  const float* __restrict__ vals, const float* __restrict__ x,
                                                  float* __restrict__ out) {
    __shared__ float logits[64][129];
    __shared__ float Qs[64][33];
    __shared__ float Ks[128][33];
    int t = threadIdx.x;
    int b = blockIdx.x / 144, tile = blockIdx.x % 144;
    int n0 = tile * 64;
    long brow = (long)b * NN;
    int r = t >> 2, sub = t & 3;

    float acc[32];
    #pragma unroll
    for (int i = 0; i < 32; i++) acc[i] = 0.0f;

    for (int k0 = 0; k0 < DD; k0 += 32) {
        __syncthreads();
        #pragma unroll
        for (int j = 0; j < 8; j++) {
            int idx = j * 256 + t;
            int rr = idx >> 5, kk = idx & 31;
            Qs[rr][kk] = P[(brow + n0 + rr) * PSTR + 384 + k0 + kk];
        }
        #pragma unroll
        for (int j = 0; j < 16; j++) {
            int idx = j * 256 + t;
            int rr = idx >> 5, kk = idx & 31;
            Ks[rr][kk] = keyv[(b * MM + rr) * DD + k0 + kk];
        }
        __syncthreads();
        for (int kk = 0; kk < 32; kk++) {
            float qv = Qs[r][kk];
            #pragma unroll
            for (int mi = 0; mi < 32; mi++) acc[mi] += qv * Ks[sub * 32 + mi][kk];
        }
    }
    #pragma unroll
    for (int mi = 0; mi < 32; mi++) logits[r][sub * 32 + mi] = acc[mi];
    __syncthreads();

    if (t < 64) {
        float mx = -1e30f;
        for (int m = 0; m < MM; m++) mx = fmaxf(mx, logits[t][m]);
        float s = 0.0f;
        for (int m = 0; m < MM; m++) { float e = __expf(logits[t][m] - mx); logits[t][m] = e; s += e; }
        float rs = 1.0f / s;
        for (int m = 0; m < MM; m++) logits[t][m] *= rs;
    }
    __syncthreads();

    int c0 = t, c1 = t + 256;
    for (int rb = 0; rb < 8; rb++) {
        float a0[8] = {}, a1[8] = {};
        for (int m = 0; m < MM; m++) {
            float v0 = vals[(b * MM + m) * CC + c0];
            float v1 = vals[(b * MM + m) * CC + c1];
            #pragma unroll
            for (int i = 0; i < 8; i++) {
                float w = logits[rb * 8 + i][m];
                a0[i] += w * v0;
                a1[i] += w * v1;
            }
        }
        #pragma unroll
        for (int i = 0; i < 8; i++) {
            long gi = (brow + n0 + rb * 8 + i) * (long)CC;
            out[gi + c0] = fmaxf(x[gi + c0] + a0[i], 0.0f);
            out[gi + c1] = fmaxf(x[gi + c1] + a1[i], 0.0f);
        }
    }
}

extern "C" void kernel_launch(void* const* d_in, const int* in_sizes, int n_in,
                              void* d_out, int out_size, void* d_ws, size_t ws_size,
                              hipStream_t stream) {
    const float* x    = (const float*)d_in[0];
    const float* adj  = (const float*)d_in[1];
    const float* emb  = (const float*)d_in[2];
    const float* Wv   = (const float*)d_in[3];
    const float* bv   = (const float*)d_in[4];
    const float* Wt   = (const float*)d_in[5];
    const float* bt   = (const float*)d_in[6];
    const float* Wg   = (const float*)d_in[7];
    const float* bg   = (const float*)d_in[8];
    const float* Wql  = (const float*)d_in[9];
    const float* Wkn  = (const float*)d_in[10];
    const float* Wm   = (const float*)d_in[11];
    const float* bm   = (const float*)d_in[12];
    float* out = (float*)d_out;

    float* ws   = (float*)d_ws;
    float* Wcat = ws;
    float* bias = Wcat + 512 * PSTR;
    float* P    = bias + PSTR;
    float* node = P + (long)BN * PSTR;
    float* gcn  = node + BB * MM * DD;
    float* evo  = gcn + BB * MM * DD;
    float* keyv = evo + BB * MM * DD;
    float* vals = keyv + BB * MM * DD;

    pack_w<<<1280, 256, 0, stream>>>(Wv, bv, Wt, bt, Wql, Wcat, bias);
    proj_gemm<<<dim3(10, 1152), 256, 0, stream>>>(x, Wcat, bias, P);
    softmax_vote<<<BN / 4, 256, 0, stream>>>(P);
    hipMemsetAsync(node, 0, (size_t)BB * MM * DD * sizeof(float), stream);
    node_gemm<<<1024, 256, 0, stream>>>(P, node);
    gcn_dense<<<BB * MM, 256, 0, stream>>>(node, emb, Wg, bg, gcn);
    gcn_adj_relu<<<BB * MM, 256, 0, stream>>>(adj, gcn, evo);
    keyv_k<<<BB * MM, 256, 0, stream>>>(evo, Wkn, keyv);
    values_k<<<BB * MM, 512, 0, stream>>>(evo, Wm, bm, vals);
    attn_fused<<<BB * 144, 256, 0, stream>>>(P, keyv, vals, x, out);
}

// Round 3
// 1354.688 us; speedup vs baseline: 1.4695x; 1.4695x over previous
//
#include <hip/hip_runtime.h>
#include <hip/hip_bf16.h>

#define BB 8
#define NN 9216       // 96*96
#define BN 73728      // BB*NN
#define CC 512
#define MM 128
#define DD 256
#define KK 300
#define DK 556        // DD+KK
#define PSTR 640      // 128 vote + 256 local + 256 query

typedef __attribute__((ext_vector_type(8))) __bf16 bf16x8;
typedef __attribute__((ext_vector_type(4))) float f32x4;

// ---------------- pack [Wv | Wt | Wql] into Wcat[512][640] + bias[640] ----------------
__global__ __launch_bounds__(256) void pack_w(const float* __restrict__ Wv, const float* __restrict__ bv,
                                              const float* __restrict__ Wt, const float* __restrict__ bt,
                                              const float* __restrict__ Wql,
                                              float* __restrict__ Wcat, float* __restrict__ bias) {
    int gid = blockIdx.x * 256 + threadIdx.x;
    if (gid < 512 * PSTR) {
        int k = gid / PSTR, j = gid % PSTR;
        float v;
        if (j < 128)       v = Wv[k * 128 + j];
        else if (j < 384)  v = Wt[k * 256 + (j - 128)];
        else               v = Wql[k * 256 + (j - 384)];
        Wcat[gid] = v;
    }
    if (gid < PSTR) {
        bias[gid] = (gid < 128) ? bv[gid] : ((gid < 384) ? bt[gid - 128] : 0.0f);
    }
}

// ---------------- P[BN][640] = x[BN][512] @ Wcat[512][640] + bias ----------------
__global__ __launch_bounds__(256) void proj_gemm(const float* __restrict__ A,
                                                 const float* __restrict__ Wcat,
                                                 const float* __restrict__ bias,
                                                 float* __restrict__ P) {
    __shared__ float AsT[32][68];
    __shared__ float Bs[32][64];
    int t = threadIdx.x;
    int tx = t & 15, ty = t >> 4;
    int n0 = blockIdx.x * 64;
    long row0 = (long)blockIdx.y * 64;
    float acc[4][4] = {};
    for (int k0 = 0; k0 < 512; k0 += 32) {
        __syncthreads();
        #pragma unroll
        for (int j = 0; j < 2; j++) {
            int idx = j * 256 + t;
            int r = idx >> 3, c4 = idx & 7;
            float4 v = *(const float4*)&A[(row0 + r) * CC + k0 + c4 * 4];
            AsT[c4 * 4 + 0][r] = v.x; AsT[c4 * 4 + 1][r] = v.y;
            AsT[c4 * 4 + 2][r] = v.z; AsT[c4 * 4 + 3][r] = v.w;
            int kk = idx >> 4, c4b = idx & 15;
            *(float4*)&Bs[kk][c4b * 4] = *(const float4*)&Wcat[(k0 + kk) * PSTR + n0 + c4b * 4];
        }
        __syncthreads();
        #pragma unroll
        for (int kk = 0; kk < 32; kk++) {
            float4 a4 = *(const float4*)&AsT[kk][ty * 4];
            float4 b4 = *(const float4*)&Bs[kk][tx * 4];
            float a[4] = {a4.x, a4.y, a4.z, a4.w};
            float b[4] = {b4.x, b4.y, b4.z, b4.w};
            #pragma unroll
            for (int i = 0; i < 4; i++)
                #pragma unroll
                for (int j = 0; j < 4; j++)
                    acc[i][j] += a[i] * b[j];
        }
    }
    float4 bb = *(const float4*)&bias[n0 + tx * 4];
    float bcol[4] = {bb.x, bb.y, bb.z, bb.w};
    #pragma unroll
    for (int i = 0; i < 4; i++) {
        float4 o;
        o.x = acc[i][0] + bcol[0]; o.y = acc[i][1] + bcol[1];
        o.z = acc[i][2] + bcol[2]; o.w = acc[i][3] + bcol[3];
        *(float4*)&P[(row0 + ty * 4 + i) * PSTR + n0 + tx * 4] = o;
    }
}

// ---------------- softmax over vote columns (P[:,0:128]) ----------------
__global__ __launch_bounds__(256) void softmax_vote(float* __restrict__ P) {
    int wid = threadIdx.x >> 6, lane = threadIdx.x & 63;
    long row = (long)blockIdx.x * 4 + wid;
    float* p = &P[row * PSTR];
    float v0 = p[lane], v1 = p[lane + 64];
    float mx = fmaxf(v0, v1);
    #pragma unroll
    for (int off = 32; off; off >>= 1) mx = fmaxf(mx, __shfl_xor(mx, off));
    float e0 = __expf(v0 - mx), e1 = __expf(v1 - mx);
    float s = e0 + e1;
    #pragma unroll
    for (int off = 32; off; off >>= 1) s += __shfl_xor(s, off);
    float r = 1.0f / s;
    p[lane] = e0 * r;
    p[lane + 64] = e1 * r;
}

// ---------------- node[b][128][256] += vote^T @ local, split-K over n ----------------
__global__ __launch_bounds__(256) void node_gemm(const float* __restrict__ P, float* __restrict__ node) {
    __shared__ float Vs[32][33];
    __shared__ float Ls[32][64];
    int t = threadIdx.x;
    int blk = blockIdx.x;
    int nc = blk & 7, dt = (blk >> 3) & 3, mt = (blk >> 5) & 3, b = blk >> 7;
    int m0 = mt * 32, d0 = dt * 64, nbase = nc * 1152;
    long brow = (long)b * NN;
    int tx = t & 15, ty = t >> 4;
    float acc[2][4] = {};
    for (int nn = 0; nn < 1152; nn += 32) {
        __syncthreads();
        #pragma unroll
        for (int j = 0; j < 4; j++) {
            int idx = j * 256 + t;
            int r = idx >> 5, mm = idx & 31;
            Vs[r][mm] = P[(brow + nbase + nn + r) * PSTR + m0 + mm];
        }
        #pragma unroll
        for (int j = 0; j < 8; j++) {
            int idx = j * 256 + t;
            int r = idx >> 6, dd = idx & 63;
            Ls[r][dd] = P[(brow + nbase + nn + r) * PSTR + 128 + d0 + dd];
        }
        __syncthreads();
        #pragma unroll 8
        for (int n = 0; n < 32; n++) {
            float va[2] = {Vs[n][ty * 2], Vs[n][ty * 2 + 1]};
            float4 vb4 = *(const float4*)&Ls[n][tx * 4];
            float vb[4] = {vb4.x, vb4.y, vb4.z, vb4.w};
            #pragma unroll
            for (int i = 0; i < 2; i++)
                #pragma unroll
                for (int j = 0; j < 4; j++)
                    acc[i][j] += va[i] * vb[j];
        }
    }
    #pragma unroll
    for (int i = 0; i < 2; i++)
        #pragma unroll
        for (int j = 0; j < 4; j++)
            unsafeAtomicAdd(&node[(b * MM + m0 + ty * 2 + i) * DD + d0 + tx * 4 + j], acc[i][j]);
}

// ---------------- gcn[b][m][:] = [node_row | emb_row] @ Wg + bg ----------------
__global__ __launch_bounds__(256) void gcn_dense(const float* __restrict__ node, const float* __restrict__ emb,
                                                 const float* __restrict__ Wg, const float* __restrict__ bg,
                                                 float* __restrict__ gcn) {
    __shared__ float a[DK];
    int b = blockIdx.x >> 7, m = blockIdx.x & 127, t = threadIdx.x;
    for (int i = t; i < DK; i += 256)
        a[i] = (i < DD) ? node[(b * MM + m) * DD + i] : emb[m * KK + (i - DD)];
    __syncthreads();
    float acc = bg[t];
    for (int k = 0; k < DK; k++) acc += a[k] * Wg[k * DD + t];
    gcn[(b * MM + m) * DD + t] = acc;
}

// ---------------- evolved = relu(norm_adj @ gcn) ----------------
__global__ __launch_bounds__(256) void gcn_adj_relu(const float* __restrict__ adj, const float* __restrict__ gcn,
                                                    float* __restrict__ evo) {
    __shared__ float ar[128];
    int b = blockIdx.x >> 7, m = blockIdx.x & 127, t = threadIdx.x;
    if (t < 128) ar[t] = adj[m * MM + t];
    __syncthreads();
    float acc = 0.0f;
    for (int k = 0; k < MM; k++) acc += ar[k] * gcn[(b * MM + k) * DD + t];
    evo[(b * MM + m) * DD + t] = fmaxf(acc, 0.0f);
}

// ---------------- Kbf[b][128][256] (bf16) = evolved @ Wkn ----------------
__global__ __launch_bounds__(256) void keyv_k(const float* __restrict__ evo, const float* __restrict__ Wkn,
                                              __bf16* __restrict__ Kbf) {
    __shared__ float e[DD];
    int b = blockIdx.x >> 7, m = blockIdx.x & 127, t = threadIdx.x;
    e[t] = evo[(b * MM + m) * DD + t];
    __syncthreads();
    float acc = 0.0f;
    for (int k = 0; k < DD; k++) acc += e[k] * Wkn[k * DD + t];
    Kbf[(b * MM + m) * DD + t] = (__bf16)acc;
}

// ---------------- Vt[b][512][128] (bf16, c-major) = (evolved @ Wm + bm)^T ----------------
__global__ __launch_bounds__(512) void values_k(const float* __restrict__ evo, const float* __restrict__ Wm,
                                                const float* __restrict__ bm, __bf16* __restrict__ Vt) {
    __shared__ float e[DD];
    int b = blockIdx.x >> 7, m = blockIdx.x & 127, t = threadIdx.x;
    if (t < DD) e[t] = evo[(b * MM + m) * DD + t];
    __syncthreads();
    float acc = bm[t];
    for (int k = 0; k < DD; k++) acc += e[k] * Wm[k * CC + t];
    Vt[((long)b * CC + t) * MM + m] = (__bf16)acc;
}

// ---------------- fused attention via MFMA bf16 ----------------
// block = 4 waves x 16 q-rows = 64-row tile; all M=128, all C=512
__global__ __launch_bounds__(256, 2) void attn_mfma(const float* __restrict__ P,
                                                    const __bf16* __restrict__ Kbf,
                                                    const __bf16* __restrict__ Vt,
                                                    const float* __restrict__ x,
                                                    float* __restrict__ out) {
    __shared__ __align__(16) __bf16 Pl[4][16][136];   // per-wave P tile, +8 pad
    int t = threadIdx.x;
    int w = t >> 6, l = t & 63;
    int lo = l & 15, hi = l >> 4;
    int b = blockIdx.x / 144, tile = blockIdx.x % 144;
    int n0 = tile * 64;
    long brow = (long)b * NN;
    long qrow = brow + n0 + w * 16 + lo;               // A-frag row for this lane
    const float* Pq = P + qrow * PSTR + 384;           // query slice
    const __bf16* Kb = Kbf + (long)b * MM * DD;
    const __bf16* Vb = Vt + (long)b * CC * MM;

    // ---- QK^T:  S[q16][m128], 8 m-tiles x 8 k-steps ----
    f32x4 S[8];
    #pragma unroll
    for (int i = 0; i < 8; i++) S[i] = (f32x4){0.f, 0.f, 0.f, 0.f};

    #pragma unroll
    for (int k0 = 0; k0 < 8; k0++) {
        float4 qa = *(const float4*)(Pq + k0 * 32 + hi * 8);
        float4 qb = *(const float4*)(Pq + k0 * 32 + hi * 8 + 4);
        bf16x8 A;
        A[0] = (__bf16)qa.x; A[1] = (__bf16)qa.y; A[2] = (__bf16)qa.z; A[3] = (__bf16)qa.w;
        A[4] = (__bf16)qb.x; A[5] = (__bf16)qb.y; A[6] = (__bf16)qb.z; A[7] = (__bf16)qb.w;
        #pragma unroll
        for (int mt = 0; mt < 8; mt++) {
            bf16x8 Bf = *(const bf16x8*)(Kb + (mt * 16 + lo) * DD + k0 * 32 + hi * 8);
            S[mt] = __builtin_amdgcn_mfma_f32_16x16x32_bf16(A, Bf, S[mt], 0, 0, 0);
        }
    }

    // ---- softmax over m (row = hi*4+reg, col = mt*16+lo) ----
    float mx[4], sm[4], rs[4];
    #pragma unroll
    for (int r = 0; r < 4; r++) {
        float m0 = S[0][r];
        #pragma unroll
        for (int mt = 1; mt < 8; mt++) m0 = fmaxf(m0, S[mt][r]);
        #pragma unroll
        for (int off = 1; off < 16; off <<= 1) m0 = fmaxf(m0, __shfl_xor(m0, off));
        mx[r] = m0;
    }
    #pragma unroll
    for (int r = 0; r < 4; r++) sm[r] = 0.f;
    #pragma unroll
    for (int mt = 0; mt < 8; mt++)
        #pragma unroll
        for (int r = 0; r < 4; r++) {
            float e = __expf(S[mt][r] - mx[r]);
            S[mt][r] = e;
            sm[r] += e;
        }
    #pragma unroll
    for (int r = 0; r < 4; r++) {
        float s0 = sm[r];
        #pragma unroll
        for (int off = 1; off < 16; off <<= 1) s0 += __shfl_xor(s0, off);
        rs[r] = 1.0f / s0;
    }
    // write normalized P (bf16) to wave-private LDS tile
    #pragma unroll
    for (int mt = 0; mt < 8; mt++)
        #pragma unroll
        for (int r = 0; r < 4; r++)
            Pl[w][hi * 4 + r][mt * 16 + lo] = (__bf16)(S[mt][r] * rs[r]);

    // ---- PV: out[q16][c512] = P[q16][m128] @ V[m128][c512] ----
    f32x4 O[32];
    #pragma unroll
    for (int i = 0; i < 32; i++) O[i] = (f32x4){0.f, 0.f, 0.f, 0.f};

    #pragma unroll
    for (int mc = 0; mc < 4; mc++) {
        bf16x8 A2 = *(const bf16x8*)&Pl[w][lo][mc * 32 + hi * 8];
        #pragma unroll
        for (int ct = 0; ct < 32; ct++) {
            bf16x8 Bv = *(const bf16x8*)(Vb + (long)(ct * 16 + lo) * MM + mc * 32 + hi * 8);
            O[ct] = __builtin_amdgcn_mfma_f32_16x16x32_bf16(A2, Bv, O[ct], 0, 0, 0);
        }
    }

    // ---- epilogue: relu(x + O) ----
    #pragma unroll
    for (int ct = 0; ct < 32; ct++) {
        #pragma unroll
        for (int r = 0; r < 4; r++) {
            long gi = (brow + n0 + w * 16 + hi * 4 + r) * (long)CC + ct * 16 + lo;
            out[gi] = fmaxf(x[gi] + O[ct][r], 0.f);
        }
    }
}

extern "C" void kernel_launch(void* const* d_in, const int* in_sizes, int n_in,
                              void* d_out, int out_size, void* d_ws, size_t ws_size,
                              hipStream_t stream) {
    const float* x    = (const float*)d_in[0];
    const float* adj  = (const float*)d_in[1];
    const float* emb  = (const float*)d_in[2];
    const float* Wv   = (const float*)d_in[3];
    const float* bv   = (const float*)d_in[4];
    const float* Wt   = (const float*)d_in[5];
    const float* bt   = (const float*)d_in[6];
    const float* Wg   = (const float*)d_in[7];
    const float* bg   = (const float*)d_in[8];
    const float* Wql  = (const float*)d_in[9];
    const float* Wkn  = (const float*)d_in[10];
    const float* Wm   = (const float*)d_in[11];
    const float* bm   = (const float*)d_in[12];
    float* out = (float*)d_out;

    float* ws   = (float*)d_ws;
    float* Wcat = ws;
    float* bias = Wcat + 512 * PSTR;
    float* P    = bias + PSTR;
    float* node = P + (long)BN * PSTR;
    float* gcn  = node + BB * MM * DD;
    float* evo  = gcn + BB * MM * DD;
    __bf16* Kbf = (__bf16*)(evo + BB * MM * DD);                 // [8][128][256] bf16
    __bf16* Vt  = Kbf + (long)BB * MM * DD;                      // [8][512][128] bf16

    pack_w<<<1280, 256, 0, stream>>>(Wv, bv, Wt, bt, Wql, Wcat, bias);
    proj_gemm<<<dim3(10, 1152), 256, 0, stream>>>(x, Wcat, bias, P);
    softmax_vote<<<BN / 4, 256, 0, stream>>>(P);
    hipMemsetAsync(node, 0, (size_t)BB * MM * DD * sizeof(float), stream);
    node_gemm<<<1024, 256, 0, stream>>>(P, node);
    gcn_dense<<<BB * MM, 256, 0, stream>>>(node, emb, Wg, bg, gcn);
    gcn_adj_relu<<<BB * MM, 256, 0, stream>>>(adj, gcn, evo);
    keyv_k<<<BB * MM, 256, 0, stream>>>(evo, Wkn, Kbf);
    values_k<<<BB * MM, 512, 0, stream>>>(evo, Wm, bm, Vt);
    attn_mfma<<<BB * 144, 256, 0, stream>>>(P, Kbf, Vt, x, out);
}

// Round 4
// 829.451 us; speedup vs baseline: 2.4000x; 1.6332x over previous
//
#include <hip/hip_runtime.h>
#include <hip/hip_bf16.h>

#define BB 8
#define NN 9216       // 96*96
#define BN 73728      // BB*NN
#define CC 512
#define MM 128
#define DD 256
#define KK 300
#define DK 556        // DD+KK
#define PSTR 640      // 128 vote + 256 local + 256 query

typedef __attribute__((ext_vector_type(8))) __bf16 bf16x8;
typedef __attribute__((ext_vector_type(4))) float f32x4;

__device__ __forceinline__ void lds_load16(const void* g, void* l) {
    __builtin_amdgcn_global_load_lds(
        (const __attribute__((address_space(1))) unsigned int*)g,
        (__attribute__((address_space(3))) unsigned int*)l, 16, 0, 0);
}

// ---------------- pack [Wv | Wt | Wql]^T into WcatT[640][512] bf16 + bias[640] f32 ----------------
__global__ __launch_bounds__(256) void pack_wt(const float* __restrict__ Wv, const float* __restrict__ bv,
                                               const float* __restrict__ Wt, const float* __restrict__ bt,
                                               const float* __restrict__ Wql,
                                               __bf16* __restrict__ WcatT, float* __restrict__ bias) {
    int gid = blockIdx.x * 256 + threadIdx.x;   // gid = n*512 + k
    if (gid < PSTR * 512) {
        int n = gid >> 9, k = gid & 511;
        float v;
        if (n < 128)       v = Wv[k * 128 + n];
        else if (n < 384)  v = Wt[k * 256 + (n - 128)];
        else               v = Wql[k * 256 + (n - 384)];
        WcatT[gid] = (__bf16)v;
    }
    if (gid < PSTR) {
        bias[gid] = (gid < 128) ? bv[gid] : ((gid < 384) ? bt[gid - 128] : 0.0f);
    }
}

// ---------------- cast x (fp32) -> xb (bf16) ----------------
__global__ __launch_bounds__(256) void cast_x(const float* __restrict__ x, __bf16* __restrict__ xb) {
    long total = (long)BN * CC;
    for (long i = ((long)blockIdx.x * 256 + threadIdx.x) * 8; i < total; i += (long)gridDim.x * 256 * 8) {
        float4 a = *(const float4*)&x[i];
        float4 b = *(const float4*)&x[i + 4];
        bf16x8 o;
        o[0] = (__bf16)a.x; o[1] = (__bf16)a.y; o[2] = (__bf16)a.z; o[3] = (__bf16)a.w;
        o[4] = (__bf16)b.x; o[5] = (__bf16)b.y; o[6] = (__bf16)b.z; o[7] = (__bf16)b.w;
        *(bf16x8*)&xb[i] = o;
    }
}

// ---------------- P[BN][640] = xb @ WcatT^T + bias  (bf16 MFMA, 128x128 tile, BK=64) ----------------
// grid: dim3(5, 576); 4 waves, each wave = 64x64 sub-tile (4x4 frags of 16x16)
__global__ __launch_bounds__(256, 2) void proj_mfma(const __bf16* __restrict__ xb,
                                                    const __bf16* __restrict__ WcatT,
                                                    const float* __restrict__ bias,
                                                    float* __restrict__ P) {
    __shared__ __align__(16) __bf16 Al[128 * 64];   // [row][k] 16 KB
    __shared__ __align__(16) __bf16 Bl[128 * 64];   // [col][k] 16 KB
    int t = threadIdx.x, w = t >> 6, l = t & 63;
    int lo = l & 15, hi = l >> 4;
    int wr = w >> 1, wc = w & 1;
    int n0 = blockIdx.x * 128;
    long row0 = (long)blockIdx.y * 128;

    f32x4 acc[4][4];
    #pragma unroll
    for (int m = 0; m < 4; m++)
        #pragma unroll
        for (int n = 0; n < 4; n++) acc[m][n] = (f32x4){0.f, 0.f, 0.f, 0.f};

    int lrow = l >> 3, lcol = (l & 7) * 8;          // staging: lane covers (8-row chunk, 8-k run)
    for (int k0 = 0; k0 < 512; k0 += 64) {
        __syncthreads();
        #pragma unroll
        for (int i = 0; i < 4; i++) {
            int c = w * 4 + i;                      // chunk = 8 rows of the [128][64] tile
            lds_load16(xb + (row0 + c * 8 + lrow) * (long)CC + k0 + lcol,
                       (char*)Al + c * 1024);
            lds_load16(WcatT + (long)(n0 + c * 8 + lrow) * CC + k0 + lcol,
                       (char*)Bl + c * 1024);
        }
        __syncthreads();
        #pragma unroll
        for (int ks = 0; ks < 2; ks++) {
            bf16x8 af[4], bfr[4];
            #pragma unroll
            for (int m = 0; m < 4; m++)
                af[m] = *(const bf16x8*)&Al[(wr * 64 + m * 16 + lo) * 64 + ks * 32 + hi * 8];
            #pragma unroll
            for (int n = 0; n < 4; n++)
                bfr[n] = *(const bf16x8*)&Bl[(wc * 64 + n * 16 + lo) * 64 + ks * 32 + hi * 8];
            #pragma unroll
            for (int m = 0; m < 4; m++)
                #pragma unroll
                for (int n = 0; n < 4; n++)
                    acc[m][n] = __builtin_amdgcn_mfma_f32_16x16x32_bf16(af[m], bfr[n], acc[m][n], 0, 0, 0);
        }
    }

    float bv[4];
    #pragma unroll
    for (int n = 0; n < 4; n++) bv[n] = bias[n0 + wc * 64 + n * 16 + lo];
    #pragma unroll
    for (int m = 0; m < 4; m++)
        #pragma unroll
        for (int n = 0; n < 4; n++)
            #pragma unroll
            for (int r = 0; r < 4; r++) {
                long row = row0 + wr * 64 + m * 16 + hi * 4 + r;
                P[row * PSTR + n0 + wc * 64 + n * 16 + lo] = acc[m][n][r] + bv[n];
            }
}

// ---------------- softmax over vote columns (P[:,0:128]) ----------------
__global__ __launch_bounds__(256) void softmax_vote(float* __restrict__ P) {
    int wid = threadIdx.x >> 6, lane = threadIdx.x & 63;
    long row = (long)blockIdx.x * 4 + wid;
    float* p = &P[row * PSTR];
    float v0 = p[lane], v1 = p[lane + 64];
    float mx = fmaxf(v0, v1);
    #pragma unroll
    for (int off = 32; off; off >>= 1) mx = fmaxf(mx, __shfl_xor(mx, off));
    float e0 = __expf(v0 - mx), e1 = __expf(v1 - mx);
    float s = e0 + e1;
    #pragma unroll
    for (int off = 32; off; off >>= 1) s += __shfl_xor(s, off);
    float r = 1.0f / s;
    p[lane] = e0 * r;
    p[lane + 64] = e1 * r;
}

// ---------------- node[b][128][256] += vote^T @ local, split-K over n ----------------
__global__ __launch_bounds__(256) void node_gemm(const float* __restrict__ P, float* __restrict__ node) {
    __shared__ float Vs[32][33];
    __shared__ float Ls[32][64];
    int t = threadIdx.x;
    int blk = blockIdx.x;
    int nc = blk & 7, dt = (blk >> 3) & 3, mt = (blk >> 5) & 3, b = blk >> 7;
    int m0 = mt * 32, d0 = dt * 64, nbase = nc * 1152;
    long brow = (long)b * NN;
    int tx = t & 15, ty = t >> 4;
    float acc[2][4] = {};
    for (int nn = 0; nn < 1152; nn += 32) {
        __syncthreads();
        #pragma unroll
        for (int j = 0; j < 4; j++) {
            int idx = j * 256 + t;
            int r = idx >> 5, mm = idx & 31;
            Vs[r][mm] = P[(brow + nbase + nn + r) * PSTR + m0 + mm];
        }
        #pragma unroll
        for (int j = 0; j < 8; j++) {
            int idx = j * 256 + t;
            int r = idx >> 6, dd = idx & 63;
            Ls[r][dd] = P[(brow + nbase + nn + r) * PSTR + 128 + d0 + dd];
        }
        __syncthreads();
        #pragma unroll 8
        for (int n = 0; n < 32; n++) {
            float va[2] = {Vs[n][ty * 2], Vs[n][ty * 2 + 1]};
            float4 vb4 = *(const float4*)&Ls[n][tx * 4];
            float vb[4] = {vb4.x, vb4.y, vb4.z, vb4.w};
            #pragma unroll
            for (int i = 0; i < 2; i++)
                #pragma unroll
                for (int j = 0; j < 4; j++)
                    acc[i][j] += va[i] * vb[j];
        }
    }
    #pragma unroll
    for (int i = 0; i < 2; i++)
        #pragma unroll
        for (int j = 0; j < 4; j++)
            unsafeAtomicAdd(&node[(b * MM + m0 + ty * 2 + i) * DD + d0 + tx * 4 + j], acc[i][j]);
}

// ---------------- gcn[b][m][:] = [node_row | emb_row] @ Wg + bg ----------------
__global__ __launch_bounds__(256) void gcn_dense(const float* __restrict__ node, const float* __restrict__ emb,
                                                 const float* __restrict__ Wg, const float* __restrict__ bg,
                                                 float* __restrict__ gcn) {
    __shared__ float a[DK];
    int b = blockIdx.x >> 7, m = blockIdx.x & 127, t = threadIdx.x;
    for (int i = t; i < DK; i += 256)
        a[i] = (i < DD) ? node[(b * MM + m) * DD + i] : emb[m * KK + (i - DD)];
    __syncthreads();
    float acc = bg[t];
    for (int k = 0; k < DK; k++) acc += a[k] * Wg[k * DD + t];
    gcn[(b * MM + m) * DD + t] = acc;
}

// ---------------- evolved = relu(norm_adj @ gcn) ----------------
__global__ __launch_bounds__(256) void gcn_adj_relu(const float* __restrict__ adj, const float* __restrict__ gcn,
                                                    float* __restrict__ evo) {
    __shared__ float ar[128];
    int b = blockIdx.x >> 7, m = blockIdx.x & 127, t = threadIdx.x;
    if (t < 128) ar[t] = adj[m * MM + t];
    __syncthreads();
    float acc = 0.0f;
    for (int k = 0; k < MM; k++) acc += ar[k] * gcn[(b * MM + k) * DD + t];
    evo[(b * MM + m) * DD + t] = fmaxf(acc, 0.0f);
}

// ---------------- Kbf[b][128][256] (bf16) = evolved @ Wkn ----------------
__global__ __launch_bounds__(256) void keyv_k(const float* __restrict__ evo, const float* __restrict__ Wkn,
                                              __bf16* __restrict__ Kbf) {
    __shared__ float e[DD];
    int b = blockIdx.x >> 7, m = blockIdx.x & 127, t = threadIdx.x;
    e[t] = evo[(b * MM + m) * DD + t];
    __syncthreads();
    float acc = 0.0f;
    for (int k = 0; k < DD; k++) acc += e[k] * Wkn[k * DD + t];
    Kbf[(b * MM + m) * DD + t] = (__bf16)acc;
}

// ---------------- Vt[b][512][128] (bf16, c-major) = (evolved @ Wm + bm)^T ----------------
__global__ __launch_bounds__(512) void values_k(const float* __restrict__ evo, const float* __restrict__ Wm,
                                                const float* __restrict__ bm, __bf16* __restrict__ Vt) {
    __shared__ float e[DD];
    int b = blockIdx.x >> 7, m = blockIdx.x & 127, t = threadIdx.x;
    if (t < DD) e[t] = evo[(b * MM + m) * DD + t];
    __syncthreads();
    float acc = bm[t];
    for (int k = 0; k < DD; k++) acc += e[k] * Wm[k * CC + t];
    Vt[((long)b * CC + t) * MM + m] = (__bf16)acc;
}

// ---------------- fused attention via MFMA bf16 ----------------
__global__ __launch_bounds__(256, 2) void attn_mfma(const float* __restrict__ P,
                                                    const __bf16* __restrict__ Kbf,
                                                    const __bf16* __restrict__ Vt,
                                                    const float* __restrict__ x,
                                                    float* __restrict__ out) {
    __shared__ __align__(16) __bf16 Pl[4][16][136];
    int t = threadIdx.x;
    int w = t >> 6, l = t & 63;
    int lo = l & 15, hi = l >> 4;
    int b = blockIdx.x / 144, tile = blockIdx.x % 144;
    int n0 = tile * 64;
    long brow = (long)b * NN;
    long qrow = brow + n0 + w * 16 + lo;
    const float* Pq = P + qrow * PSTR + 384;
    const __bf16* Kb = Kbf + (long)b * MM * DD;
    const __bf16* Vb = Vt + (long)b * CC * MM;

    f32x4 S[8];
    #pragma unroll
    for (int i = 0; i < 8; i++) S[i] = (f32x4){0.f, 0.f, 0.f, 0.f};

    #pragma unroll
    for (int k0 = 0; k0 < 8; k0++) {
        float4 qa = *(const float4*)(Pq + k0 * 32 + hi * 8);
        float4 qb = *(const float4*)(Pq + k0 * 32 + hi * 8 + 4);
        bf16x8 A;
        A[0] = (__bf16)qa.x; A[1] = (__bf16)qa.y; A[2] = (__bf16)qa.z; A[3] = (__bf16)qa.w;
        A[4] = (__bf16)qb.x; A[5] = (__bf16)qb.y; A[6] = (__bf16)qb.z; A[7] = (__bf16)qb.w;
        #pragma unroll
        for (int mt = 0; mt < 8; mt++) {
            bf16x8 Bf = *(const bf16x8*)(Kb + (mt * 16 + lo) * DD + k0 * 32 + hi * 8);
            S[mt] = __builtin_amdgcn_mfma_f32_16x16x32_bf16(A, Bf, S[mt], 0, 0, 0);
        }
    }

    float mx[4], sm[4], rs[4];
    #pragma unroll
    for (int r = 0; r < 4; r++) {
        float m0 = S[0][r];
        #pragma unroll
        for (int mt = 1; mt < 8; mt++) m0 = fmaxf(m0, S[mt][r]);
        #pragma unroll
        for (int off = 1; off < 16; off <<= 1) m0 = fmaxf(m0, __shfl_xor(m0, off));
        mx[r] = m0;
    }
    #pragma unroll
    for (int r = 0; r < 4; r++) sm[r] = 0.f;
    #pragma unroll
    for (int mt = 0; mt < 8; mt++)
        #pragma unroll
        for (int r = 0; r < 4; r++) {
            float e = __expf(S[mt][r] - mx[r]);
            S[mt][r] = e;
            sm[r] += e;
        }
    #pragma unroll
    for (int r = 0; r < 4; r++) {
        float s0 = sm[r];
        #pragma unroll
        for (int off = 1; off < 16; off <<= 1) s0 += __shfl_xor(s0, off);
        rs[r] = 1.0f / s0;
    }
    #pragma unroll
    for (int mt = 0; mt < 8; mt++)
        #pragma unroll
        for (int r = 0; r < 4; r++)
            Pl[w][hi * 4 + r][mt * 16 + lo] = (__bf16)(S[mt][r] * rs[r]);

    f32x4 O[32];
    #pragma unroll
    for (int i = 0; i < 32; i++) O[i] = (f32x4){0.f, 0.f, 0.f, 0.f};

    #pragma unroll
    for (int mc = 0; mc < 4; mc++) {
        bf16x8 A2 = *(const bf16x8*)&Pl[w][lo][mc * 32 + hi * 8];
        #pragma unroll
        for (int ct = 0; ct < 32; ct++) {
            bf16x8 Bv = *(const bf16x8*)(Vb + (long)(ct * 16 + lo) * MM + mc * 32 + hi * 8);
            O[ct] = __builtin_amdgcn_mfma_f32_16x16x32_bf16(A2, Bv, O[ct], 0, 0, 0);
        }
    }

    #pragma unroll
    for (int ct = 0; ct < 32; ct++) {
        #pragma unroll
        for (int r = 0; r < 4; r++) {
            long gi = (brow + n0 + w * 16 + hi * 4 + r) * (long)CC + ct * 16 + lo;
            out[gi] = fmaxf(x[gi] + O[ct][r], 0.f);
        }
    }
}

extern "C" void kernel_launch(void* const* d_in, const int* in_sizes, int n_in,
                              void* d_out, int out_size, void* d_ws, size_t ws_size,
                              hipStream_t stream) {
    const float* x    = (const float*)d_in[0];
    const float* adj  = (const float*)d_in[1];
    const float* emb  = (const float*)d_in[2];
    const float* Wv   = (const float*)d_in[3];
    const float* bv   = (const float*)d_in[4];
    const float* Wt   = (const float*)d_in[5];
    const float* bt   = (const float*)d_in[6];
    const float* Wg   = (const float*)d_in[7];
    const float* bg   = (const float*)d_in[8];
    const float* Wql  = (const float*)d_in[9];
    const float* Wkn  = (const float*)d_in[10];
    const float* Wm   = (const float*)d_in[11];
    const float* bm   = (const float*)d_in[12];
    float* out = (float*)d_out;

    float* ws    = (float*)d_ws;
    __bf16* WcatT = (__bf16*)ws;                                  // 640*512 bf16
    float* bias  = (float*)(WcatT + PSTR * 512);                  // 640 f32
    float* P     = bias + PSTR;
    float* node  = P + (long)BN * PSTR;
    float* gcn   = node + BB * MM * DD;
    float* evo   = gcn + BB * MM * DD;
    __bf16* Kbf  = (__bf16*)(evo + BB * MM * DD);                 // [8][128][256] bf16
    __bf16* Vt   = Kbf + (long)BB * MM * DD;                      // [8][512][128] bf16
    __bf16* xb   = (__bf16*)d_out;                                // scratch: dead until attn overwrites

    pack_wt<<<1280, 256, 0, stream>>>(Wv, bv, Wt, bt, Wql, WcatT, bias);
    cast_x<<<2048, 256, 0, stream>>>(x, xb);
    proj_mfma<<<dim3(5, 576), 256, 0, stream>>>(xb, WcatT, bias, P);
    softmax_vote<<<BN / 4, 256, 0, stream>>>(P);
    hipMemsetAsync(node, 0, (size_t)BB * MM * DD * sizeof(float), stream);
    node_gemm<<<1024, 256, 0, stream>>>(P, node);
    gcn_dense<<<BB * MM, 256, 0, stream>>>(node, emb, Wg, bg, gcn);
    gcn_adj_relu<<<BB * MM, 256, 0, stream>>>(adj, gcn, evo);
    keyv_k<<<BB * MM, 256, 0, stream>>>(evo, Wkn, Kbf);
    values_k<<<BB * MM, 512, 0, stream>>>(evo, Wm, bm, Vt);
    attn_mfma<<<BB * 144, 256, 0, stream>>>(P, Kbf, Vt, x, out);
}

// Round 6
// 694.883 us; speedup vs baseline: 2.8647x; 1.1937x over previous
//
#include <hip/hip_runtime.h>
#include <hip/hip_bf16.h>

#define BB 8
#define NN 9216       // 96*96
#define BN 73728      // BB*NN
#define CC 512
#define MM 128
#define DD 256
#define KK 300
#define DK 556        // DD+KK
#define PS 384        // P row: 128 vote-logits f32 | 256 query f32

typedef __attribute__((ext_vector_type(8))) __bf16 bf16x8;
typedef __attribute__((ext_vector_type(4))) __bf16 bf16x4;
typedef __attribute__((ext_vector_type(4))) float f32x4;

__device__ __forceinline__ void lds_load16(const void* g, void* l) {
    __builtin_amdgcn_global_load_lds(
        (const __attribute__((address_space(1))) unsigned int*)g,
        (__attribute__((address_space(3))) unsigned int*)l, 16, 0, 0);
}

__device__ __forceinline__ bf16x8 combine8(bf16x4 a, bf16x4 b) {
    bf16x8 r;
    r[0] = a[0]; r[1] = a[1]; r[2] = a[2]; r[3] = a[3];
    r[4] = b[0]; r[5] = b[1]; r[6] = b[2]; r[7] = b[3];
    return r;
}

// ---------------- pack [Wv | Wt | Wql]^T into WcatT[640][512] bf16 + bias[640] f32 ----------------
__global__ __launch_bounds__(256) void pack_wt(const float* __restrict__ Wv, const float* __restrict__ bv,
                                               const float* __restrict__ Wt, const float* __restrict__ bt,
                                               const float* __restrict__ Wql,
                                               __bf16* __restrict__ WcatT, float* __restrict__ bias) {
    int gid = blockIdx.x * 256 + threadIdx.x;   // gid = n*512 + k
    if (gid < 640 * 512) {
        int n = gid >> 9, k = gid & 511;
        float v;
        if (n < 128)       v = Wv[k * 128 + n];
        else if (n < 384)  v = Wt[k * 256 + (n - 128)];
        else               v = Wql[k * 256 + (n - 384)];
        WcatT[gid] = (__bf16)v;
    }
    if (gid < 640) {
        bias[gid] = (gid < 128) ? bv[gid] : ((gid < 384) ? bt[gid - 128] : 0.0f);
    }
}

// ---------------- cast x (fp32) -> xb (bf16) ----------------
__global__ __launch_bounds__(256) void cast_x(const float* __restrict__ x, __bf16* __restrict__ xb) {
    long total = (long)BN * CC;
    for (long i = ((long)blockIdx.x * 256 + threadIdx.x) * 8; i < total; i += (long)gridDim.x * 256 * 8) {
        float4 a = *(const float4*)&x[i];
        float4 b = *(const float4*)&x[i + 4];
        bf16x8 o;
        o[0] = (__bf16)a.x; o[1] = (__bf16)a.y; o[2] = (__bf16)a.z; o[3] = (__bf16)a.w;
        o[4] = (__bf16)b.x; o[5] = (__bf16)b.y; o[6] = (__bf16)b.z; o[7] = (__bf16)b.w;
        *(bf16x8*)&xb[i] = o;
    }
}

// ---------------- proj: xb @ WcatT^T + bias -> {P vote f32, localbf bf16, P query f32} ----------------
// grid: dim3(5, 576); 128x128 tile, BK=64, 4 waves
__global__ __launch_bounds__(256, 2) void proj_mfma(const __bf16* __restrict__ xb,
                                                    const __bf16* __restrict__ WcatT,
                                                    const float* __restrict__ bias,
                                                    float* __restrict__ P,
                                                    __bf16* __restrict__ localbf) {
    __shared__ __align__(16) __bf16 Al[128 * 64];
    __shared__ __align__(16) __bf16 Bl[128 * 64];
    int t = threadIdx.x, w = t >> 6, l = t & 63;
    int lo = l & 15, hi = l >> 4;
    int wr = w >> 1, wc = w & 1;
    int n0 = blockIdx.x * 128;
    long row0 = (long)blockIdx.y * 128;

    f32x4 acc[4][4];
    #pragma unroll
    for (int m = 0; m < 4; m++)
        #pragma unroll
        for (int n = 0; n < 4; n++) acc[m][n] = (f32x4){0.f, 0.f, 0.f, 0.f};

    int lrow = l >> 3, lcol = (l & 7) * 8;
    for (int k0 = 0; k0 < 512; k0 += 64) {
        __syncthreads();
        #pragma unroll
        for (int i = 0; i < 4; i++) {
            int c = w * 4 + i;
            lds_load16(xb + (row0 + c * 8 + lrow) * (long)CC + k0 + lcol,
                       (char*)Al + c * 1024);
            lds_load16(WcatT + (long)(n0 + c * 8 + lrow) * CC + k0 + lcol,
                       (char*)Bl + c * 1024);
        }
        __syncthreads();
        #pragma unroll
        for (int ks = 0; ks < 2; ks++) {
            bf16x8 af[4], bfr[4];
            #pragma unroll
            for (int m = 0; m < 4; m++)
                af[m] = *(const bf16x8*)&Al[(wr * 64 + m * 16 + lo) * 64 + ks * 32 + hi * 8];
            #pragma unroll
            for (int n = 0; n < 4; n++)
                bfr[n] = *(const bf16x8*)&Bl[(wc * 64 + n * 16 + lo) * 64 + ks * 32 + hi * 8];
            #pragma unroll
            for (int m = 0; m < 4; m++)
                #pragma unroll
                for (int n = 0; n < 4; n++)
                    acc[m][n] = __builtin_amdgcn_mfma_f32_16x16x32_bf16(af[m], bfr[n], acc[m][n], 0, 0, 0);
        }
    }

    float bv[4];
    #pragma unroll
    for (int n = 0; n < 4; n++) bv[n] = bias[n0 + wc * 64 + n * 16 + lo];
    #pragma unroll
    for (int m = 0; m < 4; m++)
        #pragma unroll
        for (int n = 0; n < 4; n++)
            #pragma unroll
            for (int r = 0; r < 4; r++) {
                long row = row0 + wr * 64 + m * 16 + hi * 4 + r;
                int col = n0 + wc * 64 + n * 16 + lo;
                float v = acc[m][n][r] + bv[n];
                if (n0 == 0)           P[row * PS + col] = v;                       // vote logits
                else if (n0 < 384)     localbf[row * 256 + (col - 128)] = (__bf16)v; // local, bf16
                else                   P[row * PS + (col - 256)] = v;               // query
            }
}

// ---------------- softmax over vote logits -> votebf bf16 ----------------
__global__ __launch_bounds__(256) void softmax_vote(const float* __restrict__ P, __bf16* __restrict__ votebf) {
    int wid = threadIdx.x >> 6, lane = threadIdx.x & 63;
    long row = (long)blockIdx.x * 4 + wid;
    const float* p = &P[row * PS];
    float v0 = p[lane], v1 = p[lane + 64];
    float mx = fmaxf(v0, v1);
    #pragma unroll
    for (int off = 32; off; off >>= 1) mx = fmaxf(mx, __shfl_xor(mx, off));
    float e0 = __expf(v0 - mx), e1 = __expf(v1 - mx);
    float s = e0 + e1;
    #pragma unroll
    for (int off = 32; off; off >>= 1) s += __shfl_xor(s, off);
    float r = 1.0f / s;
    votebf[row * 128 + lane] = (__bf16)(e0 * r);
    votebf[row * 128 + lane + 64] = (__bf16)(e1 * r);
}

// ---------------- node[b][128][256] += vote^T @ local  (bf16 MFMA, transposed LDS staging) ----------------
// grid: 8 b x 36 slices (256 n each); 4 waves, wave w owns d-slab [w*64, w*64+64)
__global__ __launch_bounds__(256) void node_mfma(const __bf16* __restrict__ votebf,
                                                 const __bf16* __restrict__ localbf,
                                                 float* __restrict__ node) {
    __shared__ __align__(16) __bf16 Vl[128][68];   // [m][n-chunk 64] +4 pad
    __shared__ __align__(16) __bf16 Ll[256][68];   // [d][n-chunk 64] +4 pad
    int t = threadIdx.x, w = t >> 6, l = t & 63;
    int lo = l & 15, hi = l >> 4;
    int b = blockIdx.x / 36, slice = blockIdx.x % 36;
    long base = (long)b * NN + slice * 256;

    f32x4 acc[8][4];
    #pragma unroll
    for (int mt = 0; mt < 8; mt++)
        #pragma unroll
        for (int dt = 0; dt < 4; dt++) acc[mt][dt] = (f32x4){0.f, 0.f, 0.f, 0.f};

    int mcol = t & 127, qh = t >> 7;
    for (int c0 = 0; c0 < 256; c0 += 64) {
        __syncthreads();
        // stage vote^T: Vl[m][n] <- votebf[base+c0+n][m]
        #pragma unroll
        for (int j = 0; j < 8; j++) {
            int q = j * 2 + qh;
            long n = base + c0 + q * 4;
            bf16x4 pk;
            pk[0] = votebf[n * 128 + mcol];
            pk[1] = votebf[(n + 1) * 128 + mcol];
            pk[2] = votebf[(n + 2) * 128 + mcol];
            pk[3] = votebf[(n + 3) * 128 + mcol];
            *(bf16x4*)&Vl[mcol][q * 4] = pk;
        }
        // stage local^T: Ll[d][n] <- localbf[base+c0+n][d]
        #pragma unroll
        for (int q = 0; q < 16; q++) {
            long n = base + c0 + q * 4;
            bf16x4 pk;
            pk[0] = localbf[n * 256 + t];
            pk[1] = localbf[(n + 1) * 256 + t];
            pk[2] = localbf[(n + 2) * 256 + t];
            pk[3] = localbf[(n + 3) * 256 + t];
            *(bf16x4*)&Ll[t][q * 4] = pk;
        }
        __syncthreads();
        #pragma unroll
        for (int ks = 0; ks < 2; ks++) {
            bf16x8 bfr[4];
            #pragma unroll
            for (int dt = 0; dt < 4; dt++)
                bfr[dt] = combine8(*(const bf16x4*)&Ll[w * 64 + dt * 16 + lo][ks * 32 + hi * 8],
                                   *(const bf16x4*)&Ll[w * 64 + dt * 16 + lo][ks * 32 + hi * 8 + 4]);
            #pragma unroll
            for (int mt = 0; mt < 8; mt++) {
                bf16x8 A = combine8(*(const bf16x4*)&Vl[mt * 16 + lo][ks * 32 + hi * 8],
                                    *(const bf16x4*)&Vl[mt * 16 + lo][ks * 32 + hi * 8 + 4]);
                #pragma unroll
                for (int dt = 0; dt < 4; dt++)
                    acc[mt][dt] = __builtin_amdgcn_mfma_f32_16x16x32_bf16(A, bfr[dt], acc[mt][dt], 0, 0, 0);
            }
        }
    }
    #pragma unroll
    for (int mt = 0; mt < 8; mt++)
        #pragma unroll
        for (int dt = 0; dt < 4; dt++)
            #pragma unroll
            for (int r = 0; r < 4; r++)
                unsafeAtomicAdd(&node[((long)b * MM + mt * 16 + hi * 4 + r) * DD + w * 64 + dt * 16 + lo],
                                acc[mt][dt][r]);
}

// ---------------- gcn[b][m][:] = [node_row | emb_row] @ Wg + bg ----------------
__global__ __launch_bounds__(256) void gcn_dense(const float* __restrict__ node, const float* __restrict__ emb,
                                                 const float* __restrict__ Wg, const float* __restrict__ bg,
                                                 float* __restrict__ gcn) {
    __shared__ float a[DK];
    int b = blockIdx.x >> 7, m = blockIdx.x & 127, t = threadIdx.x;
    for (int i = t; i < DK; i += 256)
        a[i] = (i < DD) ? node[(b * MM + m) * DD + i] : emb[m * KK + (i - DD)];
    __syncthreads();
    float acc = bg[t];
    for (int k = 0; k < DK; k++) acc += a[k] * Wg[k * DD + t];
    gcn[(b * MM + m) * DD + t] = acc;
}

// ---------------- evolved = relu(norm_adj @ gcn) ----------------
__global__ __launch_bounds__(256) void gcn_adj_relu(const float* __restrict__ adj, const float* __restrict__ gcn,
                                                    float* __restrict__ evo) {
    __shared__ float ar[128];
    int b = blockIdx.x >> 7, m = blockIdx.x & 127, t = threadIdx.x;
    if (t < 128) ar[t] = adj[m * MM + t];
    __syncthreads();
    float acc = 0.0f;
    for (int k = 0; k < MM; k++) acc += ar[k] * gcn[(b * MM + k) * DD + t];
    evo[(b * MM + m) * DD + t] = fmaxf(acc, 0.0f);
}

// ---------------- Kbf[b][128][256] (bf16) = evolved @ Wkn ----------------
__global__ __launch_bounds__(256) void keyv_k(const float* __restrict__ evo, const float* __restrict__ Wkn,
                                              __bf16* __restrict__ Kbf) {
    __shared__ float e[DD];
    int b = blockIdx.x >> 7, m = blockIdx.x & 127, t = threadIdx.x;
    e[t] = evo[(b * MM + m) * DD + t];
    __syncthreads();
    float acc = 0.0f;
    for (int k = 0; k < DD; k++) acc += e[k] * Wkn[k * DD + t];
    Kbf[(b * MM + m) * DD + t] = (__bf16)acc;
}

// ---------------- Vt[b][512][128] (bf16, c-major) = (evolved @ Wm + bm)^T ----------------
__global__ __launch_bounds__(512) void values_k(const float* __restrict__ evo, const float* __restrict__ Wm,
                                                const float* __restrict__ bm, __bf16* __restrict__ Vt) {
    __shared__ float e[DD];
    int b = blockIdx.x >> 7, m = blockIdx.x & 127, t = threadIdx.x;
    if (t < DD) e[t] = evo[(b * MM + m) * DD + t];
    __syncthreads();
    float acc = bm[t];
    for (int k = 0; k < DD; k++) acc += e[k] * Wm[k * CC + t];
    Vt[((long)b * CC + t) * MM + m] = (__bf16)acc;
}

// ---------------- fused attention via MFMA bf16 ----------------
__global__ __launch_bounds__(256, 2) void attn_mfma(const float* __restrict__ P,
                                                    const __bf16* __restrict__ Kbf,
                                                    const __bf16* __restrict__ Vt,
                                                    const float* __restrict__ x,
                                                    float* __restrict__ out) {
    __shared__ __align__(16) __bf16 Pl[4][16][136];
    int t = threadIdx.x;
    int w = t >> 6, l = t & 63;
    int lo = l & 15, hi = l >> 4;
    int b = blockIdx.x / 144, tile = blockIdx.x % 144;
    int n0 = tile * 64;
    long brow = (long)b * NN;
    long qrow = brow + n0 + w * 16 + lo;
    const float* Pq = P + qrow * PS + 128;
    const __bf16* Kb = Kbf + (long)b * MM * DD;
    const __bf16* Vb = Vt + (long)b * CC * MM;

    f32x4 S[8];
    #pragma unroll
    for (int i = 0; i < 8; i++) S[i] = (f32x4){0.f, 0.f, 0.f, 0.f};

    #pragma unroll
    for (int k0 = 0; k0 < 8; k0++) {
        float4 qa = *(const float4*)(Pq + k0 * 32 + hi * 8);
        float4 qb = *(const float4*)(Pq + k0 * 32 + hi * 8 + 4);
        bf16x8 A;
        A[0] = (__bf16)qa.x; A[1] = (__bf16)qa.y; A[2] = (__bf16)qa.z; A[3] = (__bf16)qa.w;
        A[4] = (__bf16)qb.x; A[5] = (__bf16)qb.y; A[6] = (__bf16)qb.z; A[7] = (__bf16)qb.w;
        #pragma unroll
        for (int mt = 0; mt < 8; mt++) {
            bf16x8 Bf = *(const bf16x8*)(Kb + (mt * 16 + lo) * DD + k0 * 32 + hi * 8);
            S[mt] = __builtin_amdgcn_mfma_f32_16x16x32_bf16(A, Bf, S[mt], 0, 0, 0);
        }
    }

    float mx[4], sm[4], rs[4];
    #pragma unroll
    for (int r = 0; r < 4; r++) {
        float m0 = S[0][r];
        #pragma unroll
        for (int mt = 1; mt < 8; mt++) m0 = fmaxf(m0, S[mt][r]);
        #pragma unroll
        for (int off = 1; off < 16; off <<= 1) m0 = fmaxf(m0, __shfl_xor(m0, off));
        mx[r] = m0;
    }
    #pragma unroll
    for (int r = 0; r < 4; r++) sm[r] = 0.f;
    #pragma unroll
    for (int mt = 0; mt < 8; mt++)
        #pragma unroll
        for (int r = 0; r < 4; r++) {
            float e = __expf(S[mt][r] - mx[r]);
            S[mt][r] = e;
            sm[r] += e;
        }
    #pragma unroll
    for (int r = 0; r < 4; r++) {
        float s0 = sm[r];
        #pragma unroll
        for (int off = 1; off < 16; off <<= 1) s0 += __shfl_xor(s0, off);
        rs[r] = 1.0f / s0;
    }
    #pragma unroll
    for (int mt = 0; mt < 8; mt++)
        #pragma unroll
        for (int r = 0; r < 4; r++)
            Pl[w][hi * 4 + r][mt * 16 + lo] = (__bf16)(S[mt][r] * rs[r]);

    f32x4 O[32];
    #pragma unroll
    for (int i = 0; i < 32; i++) O[i] = (f32x4){0.f, 0.f, 0.f, 0.f};

    #pragma unroll
    for (int mc = 0; mc < 4; mc++) {
        bf16x8 A2 = *(const bf16x8*)&Pl[w][lo][mc * 32 + hi * 8];
        #pragma unroll
        for (int ct = 0; ct < 32; ct++) {
            bf16x8 Bv = *(const bf16x8*)(Vb + (long)(ct * 16 + lo) * MM + mc * 32 + hi * 8);
            O[ct] = __builtin_amdgcn_mfma_f32_16x16x32_bf16(A2, Bv, O[ct], 0, 0, 0);
        }
    }

    #pragma unroll
    for (int ct = 0; ct < 32; ct++) {
        #pragma unroll
        for (int r = 0; r < 4; r++) {
            long gi = (brow + n0 + w * 16 + hi * 4 + r) * (long)CC + ct * 16 + lo;
            out[gi] = fmaxf(x[gi] + O[ct][r], 0.f);
        }
    }
}

extern "C" void kernel_launch(void* const* d_in, const int* in_sizes, int n_in,
                              void* d_out, int out_size, void* d_ws, size_t ws_size,
                              hipStream_t stream) {
    const float* x    = (const float*)d_in[0];
    const float* adj  = (const float*)d_in[1];
    const float* emb  = (const float*)d_in[2];
    const float* Wv   = (const float*)d_in[3];
    const float* bv   = (const float*)d_in[4];
    const float* Wt   = (const float*)d_in[5];
    const float* bt   = (const float*)d_in[6];
    const float* Wg   = (const float*)d_in[7];
    const float* bg   = (const float*)d_in[8];
    const float* Wql  = (const float*)d_in[9];
    const float* Wkn  = (const float*)d_in[10];
    const float* Wm   = (const float*)d_in[11];
    const float* bm   = (const float*)d_in[12];
    float* out = (float*)d_out;

    float* ws      = (float*)d_ws;
    __bf16* WcatT  = (__bf16*)ws;                                 // 640*512 bf16
    float* bias    = (float*)(WcatT + 640 * 512);                 // 640 f32
    float* P       = bias + 640;                                  // [BN][384] f32
    __bf16* localbf = (__bf16*)(P + (long)BN * PS);               // [BN][256] bf16
    __bf16* votebf  = localbf + (long)BN * 256;                   // [BN][128] bf16
    float* node    = (float*)(votebf + (long)BN * 128);           // [8][128][256] f32
    float* gcn     = node + BB * MM * DD;
    float* evo     = gcn + BB * MM * DD;
    __bf16* Kbf    = (__bf16*)(evo + BB * MM * DD);               // [8][128][256] bf16
    __bf16* Vt     = Kbf + (long)BB * MM * DD;                    // [8][512][128] bf16
    __bf16* xb     = (__bf16*)d_out;                              // scratch: dead until attn overwrites

    pack_wt<<<1280, 256, 0, stream>>>(Wv, bv, Wt, bt, Wql, WcatT, bias);
    cast_x<<<2048, 256, 0, stream>>>(x, xb);
    proj_mfma<<<dim3(5, 576), 256, 0, stream>>>(xb, WcatT, bias, P, localbf);
    softmax_vote<<<BN / 4, 256, 0, stream>>>(P, votebf);
    hipMemsetAsync(node, 0, (size_t)BB * MM * DD * sizeof(float), stream);
    node_mfma<<<BB * 36, 256, 0, stream>>>(votebf, localbf, node);
    gcn_dense<<<BB * MM, 256, 0, stream>>>(node, emb, Wg, bg, gcn);
    gcn_adj_relu<<<BB * MM, 256, 0, stream>>>(adj, gcn, evo);
    keyv_k<<<BB * MM, 256, 0, stream>>>(evo, Wkn, Kbf);
    values_k<<<BB * MM, 512, 0, stream>>>(evo, Wm, bm, Vt);
    attn_mfma<<<BB * 144, 256, 0, stream>>>(P, Kbf, Vt, x, out);
}